// Round 11
// baseline (144.497 us; speedup 1.0000x reference)
//
#include <hip/hip_runtime.h>
#include <hip/hip_bf16.h>

#define BATCH 16384
#define DIM   512
#define UNITS 1024
// GAMMA = 0.5 folded into epilogue: out = exp(cross - 0.5*xsq - 0.5*musq)

typedef float v16f __attribute__((ext_vector_type(16)));

#define BPITCH 33
#define APITCH 520   // fp8 LDS row pitch (bytes): b64 frag reads 2-way (free)

// prep-B: mu [DIM][UNITS] fp32 -> B8f fragment-order fp8 + musq.
// B8f layout: byte ((ng*32 + kw)*64 + lane)*8, ng = n/32, kw = k/16.
//   Lane l holds B[kw*16 + (l>>5)*8 + 0..7][ng*32 + (l&31)].
__global__ __launch_bounds__(256)
void prep_b_kernel(const float* __restrict__ mu, unsigned char* __restrict__ B8f,
                   float* __restrict__ musq) {
    __shared__ __attribute__((aligned(16))) char smem[512 * BPITCH * 4 + 1024];
    float* lds = (float*)smem;                       // [512][BPITCH]
    float* red = (float*)(smem + 512 * BPITCH * 4);  // [32][8]
    const int t  = threadIdx.x;
    const int l  = t & 63, w = t >> 6;
    const int ln = l & 31, h = l >> 5;
    const int nb = blockIdx.x;
    const int n0 = nb * 32;
    const int col = t & 31, kg = t >> 5;
    float s = 0.f;
    for (int i = 0; i < 64; i++) {
        const int k = i * 8 + kg;
        float v = mu[(size_t)k * UNITS + n0 + col];
        s += v * v;
        lds[k * BPITCH + col] = v;
    }
    red[col * 8 + kg] = s;
    __syncthreads();
    if (t < 32) {
        float a = 0.f;
#pragma unroll
        for (int i = 0; i < 8; i++) a += red[t * 8 + i];
        musq[n0 + t] = a;
    }
#pragma unroll
    for (int j = 0; j < 8; j++) {
        const int kw = w * 8 + j;
        const float* p = lds + (kw * 16 + h * 8) * BPITCH + ln;
        float f[8];
#pragma unroll
        for (int i = 0; i < 8; i++) f[i] = p[i * BPITCH];
        int lo = __builtin_amdgcn_cvt_pk_fp8_f32(f[0], f[1], 0, false);
        lo     = __builtin_amdgcn_cvt_pk_fp8_f32(f[2], f[3], lo, true);
        int hi = __builtin_amdgcn_cvt_pk_fp8_f32(f[4], f[5], 0, false);
        hi     = __builtin_amdgcn_cvt_pk_fp8_f32(f[6], f[7], hi, true);
        *(int2*)(B8f + (((size_t)nb * 32 + kw) * 64 + l) * 8) = make_int2(lo, hi);
    }
}

// Fused convert+GEMM+RBF. 1024 blocks x 256 thr (4 waves), 2 blocks/CU
// (LDS ~65.5 KB). Block tile 128M x 128N.
// Stage 1: wave w stages rows [w*32, w*32+32): coalesced fp32 float4 reads
//   (1 KB/inst), in-register fp8 cvt, row-major LDS (pitch 520 -> 2-way
//   writes/reads, free), per-row ||x||^2 shfl-reduced into LDS. A never
//   round-trips HBM as fp8; xsq needs no separate global pass.
// Stage 2 (ONE barrier): barrier-free kw-loop: 2 ds_read_b64 A-frags +
//   2 coalesced global b64 B-frags (B8f = 512 KB, L2-resident per XCD) +
//   4 MFMAs, unroll 4.
// XCD map: XCD x owns m-tiles [x*16, x*16+16); consecutive same-XCD blocks
// share an m-tile -> the 8x fp32 A re-reads are L2 hits (HBM sees 33.5 MB).
__global__ __launch_bounds__(256, 4)
void rbf_fused_kernel(const float* __restrict__ in,
                      const unsigned char* __restrict__ B8f,
                      const float* __restrict__ musq,
                      float* __restrict__ out) {
    __shared__ __attribute__((aligned(16))) char smem[128 * APITCH + 512];
    unsigned char* A8 = (unsigned char*)smem;        // [128][APITCH] fp8
    float* xsql = (float*)(smem + 128 * APITCH);     // [128] row ||x||^2

    const int t  = threadIdx.x;
    const int l  = t & 63;
    const int w  = t >> 6;          // wave 0..3
    const int ln = l & 31;
    const int h  = l >> 5;

    const int b  = blockIdx.x;      // 0..1023
    const int x  = b & 7;           // XCD (round-robin dispatch)
    const int j  = b >> 3;          // 0..127 within XCD
    const int m0 = (x * 16 + (j >> 3)) * 128;   // m-tile; 8 consecutive
    const int n0 = (j & 7) * 128;               // same-XCD blocks share it

    // ---- Stage 1: fp32 -> fp8 LDS tile + xsq ----
    const int rbase = w * 32;
    const float4* asrc = (const float4*)(in + (size_t)(m0 + rbase) * DIM);
#pragma unroll 4
    for (int rr = 0; rr < 32; rr++) {
        float4 u = asrc[rr * 128 + l];          // cols l*4
        float4 v = asrc[rr * 128 + 64 + l];     // cols 256 + l*4
        float ss = u.x * u.x + u.y * u.y + u.z * u.z + u.w * u.w
                 + v.x * v.x + v.y * v.y + v.z * v.z + v.w * v.w;
        int pu = __builtin_amdgcn_cvt_pk_fp8_f32(u.x, u.y, 0, false);
        pu     = __builtin_amdgcn_cvt_pk_fp8_f32(u.z, u.w, pu, true);
        int pv = __builtin_amdgcn_cvt_pk_fp8_f32(v.x, v.y, 0, false);
        pv     = __builtin_amdgcn_cvt_pk_fp8_f32(v.z, v.w, pv, true);
        *(int*)(A8 + (rbase + rr) * APITCH + l * 4)       = pu;
        *(int*)(A8 + (rbase + rr) * APITCH + 256 + l * 4) = pv;
        for (int off = 32; off; off >>= 1) ss += __shfl_down(ss, off, 64);
        if (l == 0) xsql[rbase + rr] = ss;
    }
    __syncthreads();

    // ---- Stage 2: barrier-free MFMA loop ----
    const int wm = (w >> 1) * 64;   // wave sub-tile origin (tile-local)
    const int wn = (w & 1) * 64;
    const long* Bf = (const long*)B8f + (size_t)((n0 + wn) >> 5) * 2048 + l;
    const unsigned char* Ab0 = A8 + (wm + ln) * APITCH + h * 8;
    const unsigned char* Ab1 = Ab0 + 32 * APITCH;

    v16f acc[2][2];
#pragma unroll
    for (int c = 0; c < 2; c++)
#pragma unroll
        for (int g = 0; g < 2; g++) acc[c][g] = (v16f)0.f;

#pragma unroll 4
    for (int kw = 0; kw < 32; kw++) {
        long a0 = *(const long*)(Ab0 + kw * 16);
        long a1 = *(const long*)(Ab1 + kw * 16);
        long b0 = Bf[kw * 64];
        long b1 = Bf[2048 + kw * 64];
        acc[0][0] = __builtin_amdgcn_mfma_f32_32x32x16_fp8_fp8(a0, b0, acc[0][0], 0, 0, 0);
        acc[0][1] = __builtin_amdgcn_mfma_f32_32x32x16_fp8_fp8(a0, b1, acc[0][1], 0, 0, 0);
        acc[1][0] = __builtin_amdgcn_mfma_f32_32x32x16_fp8_fp8(a1, b0, acc[1][0], 0, 0, 0);
        acc[1][1] = __builtin_amdgcn_mfma_f32_32x32x16_fp8_fp8(a1, b1, acc[1][1], 0, 0, 0);
    }

    // ---- Epilogue. C/D layout (m74/m101, dtype-indep): col = l&31,
    // row = (reg&3) + 8*(reg>>2) + 4*(l>>5). xsq from LDS. ----
#pragma unroll
    for (int c = 0; c < 2; c++) {
        const int mc = wm + c * 32;                    // tile-local
        const float xv = -0.5f * xsql[mc + ln];        // lane ln: row mc+ln
#pragma unroll
        for (int g = 0; g < 2; g++) {
            const int nc = n0 + wn + g * 32;
            const float mb = -0.5f * musq[nc + ln];
#pragma unroll
            for (int r = 0; r < 16; r++) {
                const int rl = (r & 3) + 8 * (r >> 2) + 4 * h;
                const float xb = __shfl(xv, rl, 64);
                float v = __expf(acc[c][g][r] + xb + mb);
                __builtin_nontemporal_store(
                    v, out + (size_t)(m0 + mc + rl) * UNITS + nc + ln);
            }
        }
    }
}

extern "C" void kernel_launch(void* const* d_in, const int* in_sizes, int n_in,
                              void* d_out, int out_size, void* d_ws, size_t ws_size,
                              hipStream_t stream) {
    const float* inputs = (const float*)d_in[0];   // [16384, 512] fp32
    const float* mu     = (const float*)d_in[1];   // [512, 1024] fp32
    float* out = (float*)d_out;                    // [16384, 1024] fp32

    char* ws = (char*)d_ws;
    unsigned char* B8f = (unsigned char*)ws;                     // 512 KiB
    float* musq        = (float*)(ws + (size_t)UNITS * DIM);     // 4 KiB

    prep_b_kernel<<<UNITS / 32, 256, 0, stream>>>(mu, B8f, musq);
    rbf_fused_kernel<<<1024, 256, 0, stream>>>(inputs, B8f, musq, out);
}